// Round 4
// baseline (25.835 us; speedup 1.0000x reference)
//
#include <hip/hip_runtime.h>
#include <math.h>

// YUMI left-arm FK: out[b,j] = T_static_0 Rz(a0) ... T_static_j Rz(aj), 4x4.
// Memory-bound: 117.4 MB out + 7.3 MB in; fill kernels sustain ~6.7 TB/s on
// this buffer => ~18.6 us floor.
//
// R4 = R3's row-parallel compute (4 lanes/element, one 1x4 row each) + R2's
// dense LDS-staged copy-out, at 20 waves/CU (256-thr block, 64 elements,
// 31.5 KB LDS -> 5 blocks/CU). Fixes R3's two residual inefficiencies:
//   - stores: R3 wrote 16 half-lines (64B @ 448B stride) per instruction;
//     copy-out now writes contiguous 1024 B per wave (8 full 128B lines).
//   - input: coalesced LDS staging replaces 4x-redundant scattered loads.

struct Statics { float m[7][12]; };  // 3x4 row-major per joint

#define TPB   256
#define EPB   64            // elements per block
#define ROW4  28            // float4 per element
#define PAD4  29            // padded LDS stride (29 mod 8 = 5 -> 2-way b128, free)

__global__ __launch_bounds__(TPB) void fk_kernel(
    const float* __restrict__ eulers, float* __restrict__ out,
    Statics st, int B)
{
    __shared__ float  ang[EPB * 7];       // 1792 B
    __shared__ float4 obuf4[EPB * PAD4];  // 29,696 B

    const int b0 = blockIdx.x * EPB;
    int nb = B - b0; if (nb > EPB) nb = EPB;

    // Coalesced input staging: 448 floats, 256 threads -> 2 dense loads.
    {
        const int nval = nb * 7;
        for (int k = threadIdx.x; k < nval; k += TPB)
            ang[k] = eulers[(size_t)b0 * 7 + k];
    }
    __syncthreads();

    const int el = threadIdx.x >> 2;   // element within block
    const int r  = threadIdx.x & 3;    // output row this lane owns

    if (b0 + el < B) {
        const float* a = &ang[el * 7];       // 4 lanes broadcast-read (free)
        float4* orow = &obuf4[el * PAD4];

        // Trow = row r of identity.
        float t0 = (r == 0) ? 1.f : 0.f;
        float t1 = (r == 1) ? 1.f : 0.f;
        float t2 = (r == 2) ? 1.f : 0.f;
        float t3 = (r == 3) ? 1.f : 0.f;

        #pragma unroll
        for (int j = 0; j < 7; ++j) {
            float s, c;
            __sincosf(a[j], &s, &c);
            const float* S = st.m[j];  // kernarg -> SGPRs

            // Trow <- Trow @ (S @ Rz(a)); rotation factored to apply after the
            // static contraction (u = Trow.Scol0, v = Trow.Scol1).
            const float u  = fmaf(t0, S[0], fmaf(t1, S[4], t2 * S[8]));
            const float v  = fmaf(t0, S[1], fmaf(t1, S[5], t2 * S[9]));
            const float n2 = fmaf(t0, S[2], fmaf(t1, S[6], t2 * S[10]));
            const float n3 = fmaf(t0, S[3], fmaf(t1, S[7], fmaf(t2, S[11], t3)));
            t0 = fmaf(c, u, s * v);
            t1 = fmaf(c, v, -s * u);
            t2 = n2;
            t3 = n3;

            orow[j * 4 + r] = make_float4(t0, t1, t2, t3);  // ds_write_b128
        }
    }
    __syncthreads();

    // Block-cooperative dense copy-out: each wave stores a contiguous 1 KB run.
    float4* out4 = reinterpret_cast<float4*>(out) + (size_t)b0 * ROW4;
    const int total4 = nb * ROW4;
    if (nb == EPB) {
        #pragma unroll 7
        for (int q = threadIdx.x; q < EPB * ROW4; q += TPB) {
            const int row = q / ROW4;
            out4[q] = obuf4[q + row];   // +row = pad skew
        }
    } else {
        for (int q = threadIdx.x; q < total4; q += TPB) {
            const int row = q / ROW4;
            out4[q] = obuf4[q + row];
        }
    }
}

extern "C" void kernel_launch(void* const* d_in, const int* in_sizes, int n_in,
                              void* d_out, int out_size, void* d_ws, size_t ws_size,
                              hipStream_t stream) {
    const float* eulers = (const float*)d_in[0];
    float* out = (float*)d_out;
    const int B = in_sizes[0] / 7;

    // Host-side double-precision static transforms (graph-capture-safe kernarg).
    static const double TRANS[7][3] = {
        { 0.05355, 0.0725,  0.41492},
        { 0.03,    0.0,     0.1    },
        {-0.03,    0.17283, 0.0    },
        {-0.04188, 0.0,     0.07873},
        { 0.0405,  0.16461, 0.0    },
        {-0.027,   0.0,     0.10039},
        { 0.027,   0.029,   0.0    },
    };
    static const double RPY[7][3] = {
        {-0.9795,    -0.5682,    2.3155},
        { 1.5707963,  0.0,       0.0   },
        {-1.5707963,  0.0,       0.0   },
        { 1.5707963, -1.5707963, 0.0   },
        {-1.5707963,  0.0,       0.0   },
        { 1.5707963,  0.0,       0.0   },
        {-1.5707963,  0.0,       0.0   },
    };

    Statics st;
    for (int j = 0; j < 7; ++j) {
        const double r = RPY[j][0], p = RPY[j][1], y = RPY[j][2];
        const double cr = cos(r), sr = sin(r);
        const double cp = cos(p), sp = sin(p);
        const double cy = cos(y), sy = sin(y);
        const double R[3][3] = {
            { cy*cp, cy*sp*sr - sy*cr, cy*sp*cr + sy*sr },
            { sy*cp, sy*sp*sr + cy*cr, sy*sp*cr - cy*sr },
            { -sp,   cp*sr,            cp*cr            },
        };
        for (int rr = 0; rr < 3; ++rr) {
            for (int cc = 0; cc < 3; ++cc) st.m[j][rr*4+cc] = (float)R[rr][cc];
            st.m[j][rr*4+3] = (float)TRANS[j][rr];
        }
    }

    const int grid = (B + EPB - 1) / EPB;
    hipLaunchKernelGGL(fk_kernel, dim3(grid), dim3(TPB), 0, stream, eulers, out, st, B);
}